// Round 4
// baseline (504.303 us; speedup 1.0000x reference)
//
#include <hip/hip_runtime.h>
#include <hip/hip_bf16.h>

// B=16, S=2048, D=1024, OUT=1024.
// attn[b,s] = softmax_s( sum_o v[o]*relu( [hidden|c_t|enc].W[o,:] + bias[o] ) )
// c_t term hoisted to cbias[b,o]; main GEMM: A[32768,2048](bf16) x W_he[1024,2048](bf16).

typedef __attribute__((ext_vector_type(8))) short short8;
typedef __attribute__((ext_vector_type(4))) float f32x4;
typedef __attribute__((ext_vector_type(8))) unsigned short ushort8v;
typedef __attribute__((ext_vector_type(4))) unsigned short ushort4v;

#define NB 16
#define NS 2048
#define ND 1024
#define NOUT 1024
#define NM (NB * NS)   // 32768 rows
#define KHE 2048       // hidden+encoder K
#define TM 128
#define TN 128
#define BKP 32         // pipelined slab depth
#define NSLAB (KHE / BKP)

// prep_k block ranges
#define PREP_ACONV 16384
#define PREP_WCONV 2048
#define PREP_CBIAS 256
#define PREP_ZERO 32

__device__ __forceinline__ unsigned short bf16_rne(float x) {
    unsigned int u = __float_as_uint(x);
    unsigned int r = (u + 0x7fffu + ((u >> 16) & 1u)) >> 16;
    return (unsigned short)r;
}

__device__ __forceinline__ void gload_lds16(const unsigned short* g, unsigned short* l) {
    __builtin_amdgcn_global_load_lds(
        (const __attribute__((address_space(1))) void*)g,
        (__attribute__((address_space(3))) void*)l, 16, 0, 0);
}

// ---------- fused prep: A-convert | W-convert | cbias | zero-logits ----------------------
__global__ __launch_bounds__(256) void prep_k(const float* __restrict__ hidden,
                                              const float* __restrict__ enc,
                                              const float* __restrict__ c_t,
                                              const float* __restrict__ W,
                                              const float* __restrict__ bias,
                                              unsigned short* __restrict__ Abf,
                                              unsigned short* __restrict__ Wbf,
                                              float* __restrict__ cbias,
                                              float* __restrict__ logits) {
    const int bid = blockIdx.x;
    const int tid = threadIdx.x;
    if (bid < PREP_ACONV) {
        // A: [hidden|enc] fp32 -> Abf [32768][2048] bf16, 16 elems/thread
        size_t c = (size_t)bid * 256 + tid;
        size_t m = c >> 7;
        int k = (int)(c & 127) * 16;
        const float* src = (k < ND) ? (hidden + m * ND + k) : (enc + m * ND + (k - ND));
        float4 f0 = ((const float4*)src)[0];
        float4 f1 = ((const float4*)src)[1];
        float4 f2 = ((const float4*)src)[2];
        float4 f3 = ((const float4*)src)[3];
        ushort8v h0, h1;
        h0[0] = bf16_rne(f0.x); h0[1] = bf16_rne(f0.y); h0[2] = bf16_rne(f0.z); h0[3] = bf16_rne(f0.w);
        h0[4] = bf16_rne(f1.x); h0[5] = bf16_rne(f1.y); h0[6] = bf16_rne(f1.z); h0[7] = bf16_rne(f1.w);
        h1[0] = bf16_rne(f2.x); h1[1] = bf16_rne(f2.y); h1[2] = bf16_rne(f2.z); h1[3] = bf16_rne(f2.w);
        h1[4] = bf16_rne(f3.x); h1[5] = bf16_rne(f3.y); h1[6] = bf16_rne(f3.z); h1[7] = bf16_rne(f3.w);
        *(ushort8v*)(Abf + m * KHE + k) = h0;
        *(ushort8v*)(Abf + m * KHE + k + 8) = h1;
    } else if (bid < PREP_ACONV + PREP_WCONV) {
        int idx = (bid - PREP_ACONV) * 256 + tid;
        int o = idx >> 9;
        int k = (idx & 511) * 4;
        int off = (k < ND) ? k : (k + ND);
        float4 f = *(const float4*)(W + (size_t)o * 3072 + off);
        ushort4v h;
        h.x = bf16_rne(f.x); h.y = bf16_rne(f.y); h.z = bf16_rne(f.z); h.w = bf16_rne(f.w);
        *(ushort4v*)(Wbf + (size_t)o * KHE + k) = h;
    } else if (bid < PREP_ACONV + PREP_WCONV + PREP_CBIAS) {
        int o = (bid - PREP_ACONV - PREP_WCONV) * 4 + (tid >> 6);
        int lane = tid & 63;
        const float* w = W + (size_t)o * 3072 + ND;
        float wr[16];
        #pragma unroll
        for (int j = 0; j < 16; ++j) wr[j] = w[lane + j * 64];
        float bo = bias[o];
        for (int b = 0; b < NB; ++b) {
            const float* cc = c_t + (size_t)b * ND;
            float s = 0.f;
            #pragma unroll
            for (int j = 0; j < 16; ++j) s = fmaf(cc[lane + j * 64], wr[j], s);
            #pragma unroll
            for (int m = 1; m < 64; m <<= 1) s += __shfl_xor(s, m);
            if (lane == 0) cbias[b * NOUT + o] = s + bo;
        }
    } else {
        int idx = (bid - PREP_ACONV - PREP_WCONV - PREP_CBIAS) * 256 + tid;
        ((float4*)logits)[idx] = make_float4(0.f, 0.f, 0.f, 0.f);
    }
}

// ---------- standalone prep pieces (ws-fallback path only) -------------------------------
__global__ __launch_bounds__(256) void wconv_k(const float* __restrict__ W,
                                               unsigned short* __restrict__ Wbf) {
    int idx = blockIdx.x * 256 + threadIdx.x;
    int o = idx >> 9;
    int k = (idx & 511) * 4;
    int off = (k < ND) ? k : (k + ND);
    float4 f = *(const float4*)(W + (size_t)o * 3072 + off);
    ushort4v h;
    h.x = bf16_rne(f.x); h.y = bf16_rne(f.y); h.z = bf16_rne(f.z); h.w = bf16_rne(f.w);
    *(ushort4v*)(Wbf + (size_t)o * KHE + k) = h;
}

__global__ __launch_bounds__(256) void cbias_k(const float* __restrict__ c_t,
                                               const float* __restrict__ W,
                                               const float* __restrict__ bias,
                                               float* __restrict__ cbias) {
    int o = blockIdx.x * 4 + (threadIdx.x >> 6);
    int lane = threadIdx.x & 63;
    const float* w = W + (size_t)o * 3072 + ND;
    float wr[16];
    #pragma unroll
    for (int j = 0; j < 16; ++j) wr[j] = w[lane + j * 64];
    float bo = bias[o];
    for (int b = 0; b < NB; ++b) {
        const float* c = c_t + (size_t)b * ND;
        float s = 0.f;
        #pragma unroll
        for (int j = 0; j < 16; ++j) s = fmaf(c[lane + j * 64], wr[j], s);
        #pragma unroll
        for (int m = 1; m < 64; m <<= 1) s += __shfl_xor(s, m);
        if (lane == 0) cbias[b * NOUT + o] = s + bo;
    }
}

// ---------- fast GEMM: double-buffered BK=32 pipeline, one barrier/slab, XCD remap -------
// LDS: slot sigma of row rho holds global 16B-chunk sigma^(rho&3) (XOR swizzle, 4 chunks).
// Staging lane l: row l>>2, slot l&3, fetches chunk (l&3)^((l>>2)&3); HW scatters to
// ldsbase + l*16. Frag read: chunk c=lane>>4 at slot c^(lane&3) -> conflict-free.
// Pipeline: barrier (drains slab s, issued one full compute phase ago) -> issue slab s+1
// into other buffer -> compute slab s. WAR safe: buf[(s+1)&1] last read at iter s-1,
// ordered by this barrier.
__global__ __launch_bounds__(256) void gemm_att_bf_k(const unsigned short* __restrict__ Abf,
                                                     const unsigned short* __restrict__ Wbf,
                                                     const float* __restrict__ cbias,
                                                     const float* __restrict__ v,
                                                     float* __restrict__ logits) {
    __shared__ unsigned short As[2][TM * BKP] __attribute__((aligned(16)));  // 2 x 8 KiB
    __shared__ unsigned short Bs[2][TN * BKP] __attribute__((aligned(16)));  // 2 x 8 KiB
    __shared__ float rowsum[2][TM];
    __shared__ float cb_s[TN];
    __shared__ float v_s[TN];

    const int tid = threadIdx.x;
    // XCD-aware remap: bid%8 ~ XCD. Each XCD gets a contiguous 32-mtile range x all ntiles;
    // 8 temporally-adjacent slots share one A-tile in that XCD's L2.
    const int bid = blockIdx.x;
    const int xcd = bid & 7;
    const int slot = bid >> 3;
    const int mtile = xcd * 32 + (slot >> 3);
    const int ntile = slot & 7;
    const int m0 = mtile * TM;
    const int o0 = ntile * TN;
    const int batch = m0 >> 11;

    if (tid < TN) {
        cb_s[tid] = cbias[batch * NOUT + o0 + tid];
        v_s[tid] = v[o0 + tid];
    }

    const int wid = tid >> 6;
    const int lane = tid & 63;
    const int wm = (wid & 1) * 64;
    const int wn = (wid >> 1) * 64;

    // staging addresses: issue i covers rows i*64 + wid*16 + (lane>>2)
    const int srow = lane >> 2;
    const int schunk = (lane & 3) ^ (srow & 3);
    const unsigned short* agA0 = Abf + (size_t)(m0 + wid * 16 + srow) * KHE + schunk * 8;
    const unsigned short* agA1 = agA0 + (size_t)64 * KHE;
    const unsigned short* bgB0 = Wbf + (size_t)(o0 + wid * 16 + srow) * KHE + schunk * 8;
    const unsigned short* bgB1 = bgB0 + (size_t)64 * KHE;
    const int ldsA0 = (wid * 16) * BKP;          // + lane*16B scattered by HW
    const int ldsA1 = (64 + wid * 16) * BKP;

    f32x4 acc[4][4] = {};

    // prologue: slab 0 -> buffer 0
    gload_lds16(agA0, &As[0][ldsA0]);
    gload_lds16(agA1, &As[0][ldsA1]);
    gload_lds16(bgB0, &Bs[0][ldsA0]);
    gload_lds16(bgB1, &Bs[0][ldsA1]);

    for (int s = 0; s < NSLAB; ++s) {
        __syncthreads();   // drains vmcnt -> slab s resident; readers of buf[(s+1)&1] done
        if (s < NSLAB - 1) {
            const int ktn = (s + 1) * BKP;
            unsigned short* An = As[(s + 1) & 1];
            unsigned short* Bn = Bs[(s + 1) & 1];
            gload_lds16(agA0 + ktn, An + ldsA0);
            gload_lds16(agA1 + ktn, An + ldsA1);
            gload_lds16(bgB0 + ktn, Bn + ldsA0);
            gload_lds16(bgB1 + ktn, Bn + ldsA1);
        }
        const unsigned short* Ac = As[s & 1];
        const unsigned short* Bc = Bs[s & 1];
        const int fslot = ((lane >> 4) ^ (lane & 3)) * 8;
        short8 a_frag[4], b_frag[4];
        #pragma unroll
        for (int i = 0; i < 4; ++i)
            a_frag[i] = *(const short8*)(Ac + (wm + i * 16 + (lane & 15)) * BKP + fslot);
        #pragma unroll
        for (int j = 0; j < 4; ++j)
            b_frag[j] = *(const short8*)(Bc + (wn + j * 16 + (lane & 15)) * BKP + fslot);
        #pragma unroll
        for (int i = 0; i < 4; ++i)
            #pragma unroll
            for (int j = 0; j < 4; ++j)
                acc[i][j] = __builtin_amdgcn_mfma_f32_16x16x32_bf16(a_frag[i], b_frag[j],
                                                                    acc[i][j], 0, 0, 0);
    }

    // epilogue: relu(acc + cbias) * v, reduce over this block's 128 o's.
    // C/D: col = lane&15 (o), row = (lane>>4)*4 + reg (m).  (verified rounds 1-3)
    const int col = lane & 15;
    const int q = lane >> 4;
    float vv[4], cbv[4];
    #pragma unroll
    for (int j = 0; j < 4; ++j) {
        int oc = wn + j * 16 + col;
        vv[j] = v_s[oc];
        cbv[j] = cb_s[oc];
    }
    #pragma unroll
    for (int i = 0; i < 4; ++i) {
        #pragma unroll
        for (int r = 0; r < 4; ++r) {
            float s = 0.f;
            #pragma unroll
            for (int j = 0; j < 4; ++j) {
                float e = acc[i][j][r] + cbv[j];
                e = fmaxf(e, 0.f);
                s = fmaf(e, vv[j], s);
            }
            s += __shfl_xor(s, 1);
            s += __shfl_xor(s, 2);
            s += __shfl_xor(s, 4);
            s += __shfl_xor(s, 8);
            if (col == 0) rowsum[wid >> 1][wm + i * 16 + q * 4 + r] = s;
        }
    }
    __syncthreads();
    if (tid < TM) atomicAdd(&logits[m0 + tid], rowsum[0][tid] + rowsum[1][tid]);
}

// ---------- fallback GEMM (fp32 A staged+converted in-kernel, BK=32) ---------------------
__global__ __launch_bounds__(256) void gemm_att_k(const float* __restrict__ hidden,
                                                  const float* __restrict__ enc,
                                                  const unsigned short* __restrict__ Wbf,
                                                  const float* __restrict__ Wf,
                                                  const float* __restrict__ cbias,
                                                  const float* __restrict__ v,
                                                  float* __restrict__ logits,
                                                  int use_wbf) {
    __shared__ unsigned short As[TM * 32] __attribute__((aligned(16)));
    __shared__ unsigned short Bs[TN * 32] __attribute__((aligned(16)));
    __shared__ float rowsum[2][TM];
    __shared__ float cb_s[TN];
    __shared__ float v_s[TN];

    const int tid = threadIdx.x;
    const int ntile = blockIdx.x & 7;
    const int mtile = blockIdx.x >> 3;
    const int m0 = mtile * TM;
    const int o0 = ntile * TN;
    const int batch = m0 >> 11;

    if (tid < TN) {
        cb_s[tid] = cbias[batch * NOUT + o0 + tid];
        v_s[tid] = v[o0 + tid];
    }

    const int wid = tid >> 6;
    const int lane = tid & 63;
    const int wm = (wid & 1) * 64;
    const int wn = (wid >> 1) * 64;

    f32x4 acc[4][4] = {};

    for (int kt = 0; kt < KHE; kt += 32) {
        const float* Abase = (kt < ND) ? hidden : enc;
        const int aoff = (kt < ND) ? kt : (kt - ND);
        #pragma unroll
        for (int i = 0; i < 4; ++i) {
            int p = tid + i * 256;
            int row = p >> 3, kc = p & 7;
            float4 f = *(const float4*)(Abase + (size_t)(m0 + row) * ND + aoff + kc * 4);
            ushort4v h;
            h.x = bf16_rne(f.x); h.y = bf16_rne(f.y); h.z = bf16_rne(f.z); h.w = bf16_rne(f.w);
            *(ushort4v*)(As + row * 32 + kc * 4) = h;
        }
        if (use_wbf) {
            #pragma unroll
            for (int i = 0; i < 2; ++i) {
                int u = tid + i * 256;
                int ol = u >> 2, kc = u & 3;
                ushort8v w8 = *(const ushort8v*)(Wbf + (size_t)(o0 + ol) * KHE + kt + kc * 8);
                *(ushort8v*)(Bs + ol * 32 + kc * 8) = w8;
            }
        } else {
            const int woff = (kt < ND) ? kt : (kt + ND);
            #pragma unroll
            for (int i = 0; i < 4; ++i) {
                int p = tid + i * 256;
                int row = p >> 3, kc = p & 7;
                float4 f = *(const float4*)(Wf + (size_t)(o0 + row) * 3072 + woff + kc * 4);
                ushort4v h;
                h.x = bf16_rne(f.x); h.y = bf16_rne(f.y); h.z = bf16_rne(f.z); h.w = bf16_rne(f.w);
                *(ushort4v*)(Bs + row * 32 + kc * 4) = h;
            }
        }
        __syncthreads();

        short8 a_frag[4], b_frag[4];
        #pragma unroll
        for (int i = 0; i < 4; ++i)
            a_frag[i] = *(const short8*)(As + (wm + i * 16 + (lane & 15)) * 32 + (lane >> 4) * 8);
        #pragma unroll
        for (int j = 0; j < 4; ++j)
            b_frag[j] = *(const short8*)(Bs + (wn + j * 16 + (lane & 15)) * 32 + (lane >> 4) * 8);
        #pragma unroll
        for (int i = 0; i < 4; ++i)
            #pragma unroll
            for (int j = 0; j < 4; ++j)
                acc[i][j] = __builtin_amdgcn_mfma_f32_16x16x32_bf16(a_frag[i], b_frag[j],
                                                                    acc[i][j], 0, 0, 0);
        __syncthreads();
    }

    const int col = lane & 15;
    const int q = lane >> 4;
    float vv[4], cbv[4];
    #pragma unroll
    for (int j = 0; j < 4; ++j) {
        int oc = wn + j * 16 + col;
        vv[j] = v_s[oc];
        cbv[j] = cb_s[oc];
    }
    #pragma unroll
    for (int i = 0; i < 4; ++i) {
        #pragma unroll
        for (int r = 0; r < 4; ++r) {
            float s = 0.f;
            #pragma unroll
            for (int j = 0; j < 4; ++j) {
                float e = acc[i][j][r] + cbv[j];
                e = fmaxf(e, 0.f);
                s = fmaf(e, vv[j], s);
            }
            s += __shfl_xor(s, 1);
            s += __shfl_xor(s, 2);
            s += __shfl_xor(s, 4);
            s += __shfl_xor(s, 8);
            if (col == 0) rowsum[wid >> 1][wm + i * 16 + q * 4 + r] = s;
        }
    }
    __syncthreads();
    if (tid < TM) atomicAdd(&logits[m0 + tid], rowsum[0][tid] + rowsum[1][tid]);
}

// ---------- softmax over S per batch -----------------------------------------------------
__global__ __launch_bounds__(256) void softmax_k(const float* __restrict__ logits,
                                                 float* __restrict__ out) {
    const int b = blockIdx.x;
    const int tid = threadIdx.x;
    const int lane = tid & 63, wid = tid >> 6;
    __shared__ float redmax[4];
    __shared__ float redsum[4];
    const float* L = logits + (size_t)b * NS;
    float x[8];
    float mx = -3.4e38f;
    #pragma unroll
    for (int i = 0; i < 8; ++i) {
        x[i] = L[tid + i * 256];
        mx = fmaxf(mx, x[i]);
    }
    #pragma unroll
    for (int m = 1; m < 64; m <<= 1) mx = fmaxf(mx, __shfl_xor(mx, m));
    if (lane == 0) redmax[wid] = mx;
    __syncthreads();
    mx = fmaxf(fmaxf(redmax[0], redmax[1]), fmaxf(redmax[2], redmax[3]));
    float sum = 0.f;
    #pragma unroll
    for (int i = 0; i < 8; ++i) {
        x[i] = expf(x[i] - mx);
        sum += x[i];
    }
    #pragma unroll
    for (int m = 1; m < 64; m <<= 1) sum += __shfl_xor(sum, m);
    if (lane == 0) redsum[wid] = sum;
    __syncthreads();
    float inv = 1.0f / (redsum[0] + redsum[1] + redsum[2] + redsum[3]);
    #pragma unroll
    for (int i = 0; i < 8; ++i) out[(size_t)b * NS + tid + i * 256] = x[i] * inv;
}

extern "C" void kernel_launch(void* const* d_in, const int* in_sizes, int n_in,
                              void* d_out, int out_size, void* d_ws, size_t ws_size,
                              hipStream_t stream) {
    const float* hidden = (const float*)d_in[0];
    const float* enc    = (const float*)d_in[1];
    const float* c_t    = (const float*)d_in[2];
    const float* W      = (const float*)d_in[3];
    const float* bias   = (const float*)d_in[4];
    const float* v      = (const float*)d_in[5];
    float* out = (float*)d_out;

    char* ws = (char*)d_ws;
    float* logits = (float*)ws;                             // 131072 B
    float* cbias  = (float*)(ws + 131072);                  //  65536 B
    unsigned short* Wbf = (unsigned short*)(ws + 196608);   // 4 MiB
    unsigned short* Abf = (unsigned short*)(ws + 196608 + 4194304);  // 128 MiB
    const size_t need_wbf = 196608 + (size_t)NOUT * KHE * 2;
    const size_t need_abf = need_wbf + (size_t)NM * KHE * 2;

    if (ws_size >= need_abf) {
        prep_k<<<PREP_ACONV + PREP_WCONV + PREP_CBIAS + PREP_ZERO, 256, 0, stream>>>(
            hidden, enc, c_t, W, bias, Abf, Wbf, cbias, logits);
        gemm_att_bf_k<<<(NM / TM) * (NOUT / TN), 256, 0, stream>>>(Abf, Wbf, cbias, v, logits);
    } else if (ws_size >= need_wbf) {
        hipMemsetAsync(logits, 0, NM * sizeof(float), stream);
        cbias_k<<<NOUT / 4, 256, 0, stream>>>(c_t, W, bias, cbias);
        wconv_k<<<(NOUT * KHE / 4) / 256, 256, 0, stream>>>(W, Wbf);
        gemm_att_k<<<(NM / TM) * (NOUT / TN), 256, 0, stream>>>(hidden, enc, Wbf, W, cbias, v,
                                                                logits, 1);
    } else {
        hipMemsetAsync(logits, 0, NM * sizeof(float), stream);
        cbias_k<<<NOUT / 4, 256, 0, stream>>>(c_t, W, bias, cbias);
        gemm_att_k<<<(NM / TM) * (NOUT / TN), 256, 0, stream>>>(hidden, enc, Wbf, W, cbias, v,
                                                                logits, 0);
    }
    softmax_k<<<NB, 256, 0, stream>>>(logits, out);
}

// Round 5
// 501.284 us; speedup vs baseline: 1.0060x; 1.0060x over previous
//
#include <hip/hip_runtime.h>
#include <hip/hip_bf16.h>

// B=16, S=2048, D=1024, OUT=1024.
// attn[b,s] = softmax_s( sum_o v[o]*relu( [hidden|c_t|enc].W[o,:] + bias[o] ) )
// c_t term hoisted to cbias[b,o]; main GEMM: A[32768,2048](bf16) x W_he[1024,2048](bf16).
// R3: BK=64 XOR swizzle -> 0 bank conflicts. R4: XCD remap -> FETCH 532->114 MB.
// R5 = R3 GEMM + R4 remap (BK=32 dbuf abandoned: 64B row stride = 16 banks = conflicts).

typedef __attribute__((ext_vector_type(8))) short short8;
typedef __attribute__((ext_vector_type(4))) float f32x4;
typedef __attribute__((ext_vector_type(8))) unsigned short ushort8v;
typedef __attribute__((ext_vector_type(4))) unsigned short ushort4v;

#define NB 16
#define NS 2048
#define ND 1024
#define NOUT 1024
#define NM (NB * NS)   // 32768 rows
#define KHE 2048       // hidden+encoder K
#define TM 128
#define TN 128
#define BK 64

// prep_k block ranges
#define PREP_ACONV 16384
#define PREP_WCONV 2048
#define PREP_CBIAS 256
#define PREP_ZERO 32

__device__ __forceinline__ unsigned short bf16_rne(float x) {
    unsigned int u = __float_as_uint(x);
    unsigned int r = (u + 0x7fffu + ((u >> 16) & 1u)) >> 16;
    return (unsigned short)r;
}

__device__ __forceinline__ void gload_lds16(const unsigned short* g, unsigned short* l) {
    __builtin_amdgcn_global_load_lds(
        (const __attribute__((address_space(1))) void*)g,
        (__attribute__((address_space(3))) void*)l, 16, 0, 0);
}

// ---------- fused prep: A-convert | W-convert | cbias | zero-logits ----------------------
__global__ __launch_bounds__(256) void prep_k(const float* __restrict__ hidden,
                                              const float* __restrict__ enc,
                                              const float* __restrict__ c_t,
                                              const float* __restrict__ W,
                                              const float* __restrict__ bias,
                                              unsigned short* __restrict__ Abf,
                                              unsigned short* __restrict__ Wbf,
                                              float* __restrict__ cbias,
                                              float* __restrict__ logits) {
    const int bid = blockIdx.x;
    const int tid = threadIdx.x;
    if (bid < PREP_ACONV) {
        // A: [hidden|enc] fp32 -> Abf [32768][2048] bf16, 16 elems/thread
        size_t c = (size_t)bid * 256 + tid;
        size_t m = c >> 7;
        int k = (int)(c & 127) * 16;
        const float* src = (k < ND) ? (hidden + m * ND + k) : (enc + m * ND + (k - ND));
        float4 f0 = ((const float4*)src)[0];
        float4 f1 = ((const float4*)src)[1];
        float4 f2 = ((const float4*)src)[2];
        float4 f3 = ((const float4*)src)[3];
        ushort8v h0, h1;
        h0[0] = bf16_rne(f0.x); h0[1] = bf16_rne(f0.y); h0[2] = bf16_rne(f0.z); h0[3] = bf16_rne(f0.w);
        h0[4] = bf16_rne(f1.x); h0[5] = bf16_rne(f1.y); h0[6] = bf16_rne(f1.z); h0[7] = bf16_rne(f1.w);
        h1[0] = bf16_rne(f2.x); h1[1] = bf16_rne(f2.y); h1[2] = bf16_rne(f2.z); h1[3] = bf16_rne(f2.w);
        h1[4] = bf16_rne(f3.x); h1[5] = bf16_rne(f3.y); h1[6] = bf16_rne(f3.z); h1[7] = bf16_rne(f3.w);
        *(ushort8v*)(Abf + m * KHE + k) = h0;
        *(ushort8v*)(Abf + m * KHE + k + 8) = h1;
    } else if (bid < PREP_ACONV + PREP_WCONV) {
        int idx = (bid - PREP_ACONV) * 256 + tid;
        int o = idx >> 9;
        int k = (idx & 511) * 4;
        int off = (k < ND) ? k : (k + ND);
        float4 f = *(const float4*)(W + (size_t)o * 3072 + off);
        ushort4v h;
        h.x = bf16_rne(f.x); h.y = bf16_rne(f.y); h.z = bf16_rne(f.z); h.w = bf16_rne(f.w);
        *(ushort4v*)(Wbf + (size_t)o * KHE + k) = h;
    } else if (bid < PREP_ACONV + PREP_WCONV + PREP_CBIAS) {
        int o = (bid - PREP_ACONV - PREP_WCONV) * 4 + (tid >> 6);
        int lane = tid & 63;
        const float* w = W + (size_t)o * 3072 + ND;
        float wr[16];
        #pragma unroll
        for (int j = 0; j < 16; ++j) wr[j] = w[lane + j * 64];
        float bo = bias[o];
        for (int b = 0; b < NB; ++b) {
            const float* cc = c_t + (size_t)b * ND;
            float s = 0.f;
            #pragma unroll
            for (int j = 0; j < 16; ++j) s = fmaf(cc[lane + j * 64], wr[j], s);
            #pragma unroll
            for (int m = 1; m < 64; m <<= 1) s += __shfl_xor(s, m);
            if (lane == 0) cbias[b * NOUT + o] = s + bo;
        }
    } else {
        int idx = (bid - PREP_ACONV - PREP_WCONV - PREP_CBIAS) * 256 + tid;
        ((float4*)logits)[idx] = make_float4(0.f, 0.f, 0.f, 0.f);
    }
}

// ---------- standalone prep pieces (ws-fallback path only) -------------------------------
__global__ __launch_bounds__(256) void wconv_k(const float* __restrict__ W,
                                               unsigned short* __restrict__ Wbf) {
    int idx = blockIdx.x * 256 + threadIdx.x;
    int o = idx >> 9;
    int k = (idx & 511) * 4;
    int off = (k < ND) ? k : (k + ND);
    float4 f = *(const float4*)(W + (size_t)o * 3072 + off);
    ushort4v h;
    h.x = bf16_rne(f.x); h.y = bf16_rne(f.y); h.z = bf16_rne(f.z); h.w = bf16_rne(f.w);
    *(ushort4v*)(Wbf + (size_t)o * KHE + k) = h;
}

__global__ __launch_bounds__(256) void cbias_k(const float* __restrict__ c_t,
                                               const float* __restrict__ W,
                                               const float* __restrict__ bias,
                                               float* __restrict__ cbias) {
    int o = blockIdx.x * 4 + (threadIdx.x >> 6);
    int lane = threadIdx.x & 63;
    const float* w = W + (size_t)o * 3072 + ND;
    float wr[16];
    #pragma unroll
    for (int j = 0; j < 16; ++j) wr[j] = w[lane + j * 64];
    float bo = bias[o];
    for (int b = 0; b < NB; ++b) {
        const float* c = c_t + (size_t)b * ND;
        float s = 0.f;
        #pragma unroll
        for (int j = 0; j < 16; ++j) s = fmaf(c[lane + j * 64], wr[j], s);
        #pragma unroll
        for (int m = 1; m < 64; m <<= 1) s += __shfl_xor(s, m);
        if (lane == 0) cbias[b * NOUT + o] = s + bo;
    }
}

// ---------- fast GEMM: BK=64, XOR-swizzled LDS (0 conflicts), XCD-aware remap ------------
// LDS layout: As[row][slot], slot sigma of row rho holds global 16B-chunk sigma^(rho&7).
// Staging lane: row = lane>>3, fetches chunk (lane&7)^(lane>>3) -> lands at slot lane&7.
// ds_read bank = 4*(chunk ^ (row&7)) -> all 32 banks covered evenly (8-phase floor).
__global__ __launch_bounds__(256) void gemm_att_bf_k(const unsigned short* __restrict__ Abf,
                                                     const unsigned short* __restrict__ Wbf,
                                                     const float* __restrict__ cbias,
                                                     const float* __restrict__ v,
                                                     float* __restrict__ logits) {
    __shared__ unsigned short As[TM * BK] __attribute__((aligned(16)));  // 16 KiB
    __shared__ unsigned short Bs[TN * BK] __attribute__((aligned(16)));  // 16 KiB
    __shared__ float rowsum[2][TM];
    __shared__ float cb_s[TN];
    __shared__ float v_s[TN];

    const int tid = threadIdx.x;
    // XCD-aware remap (R4, FETCH 532->114 MB): bid%8 ~ XCD; each XCD owns a contiguous
    // 32-mtile range; its 8 temporally-adjacent slots share one A-tile in L2.
    const int bid = blockIdx.x;
    const int xcd = bid & 7;
    const int slot = bid >> 3;
    const int mtile = xcd * 32 + (slot >> 3);
    const int ntile = slot & 7;
    const int m0 = mtile * TM;
    const int o0 = ntile * TN;
    const int batch = m0 >> 11;

    if (tid < TN) {
        cb_s[tid] = cbias[batch * NOUT + o0 + tid];
        v_s[tid] = v[o0 + tid];
    }

    const int wid = tid >> 6;
    const int lane = tid & 63;
    const int wm = (wid & 1) * 64;
    const int wn = (wid >> 1) * 64;

    // staging: wave covers 32 rows (4 issues x 8 rows); lane -> row lane>>3, slot lane&7
    const int srow = lane >> 3;
    const int schunk = (lane & 7) ^ srow;  // swizzled global chunk
    const unsigned short* agb = Abf + (size_t)(m0 + wid * 32 + srow) * KHE + schunk * 8;
    const unsigned short* bgb = Wbf + (size_t)(o0 + wid * 32 + srow) * KHE + schunk * 8;
    unsigned short* alb = As + (wid * 32) * BK;
    unsigned short* blb = Bs + (wid * 32) * BK;

    f32x4 acc[4][4] = {};

    for (int kt = 0; kt < KHE; kt += BK) {
        #pragma unroll
        for (int t = 0; t < 4; ++t) {
            gload_lds16(agb + (size_t)(t * 8) * KHE + kt, alb + (t * 8) * BK);
            gload_lds16(bgb + (size_t)(t * 8) * KHE + kt, blb + (t * 8) * BK);
        }
        __syncthreads();

        #pragma unroll
        for (int s = 0; s < 2; ++s) {
            const int cbase = s * 4 + (lane >> 4);  // global k-chunk this lane needs
            short8 a_frag[4], b_frag[4];
            #pragma unroll
            for (int i = 0; i < 4; ++i) {
                int row = wm + i * 16 + (lane & 15);
                a_frag[i] = *(const short8*)(As + row * BK + ((cbase ^ (row & 7)) * 8));
            }
            #pragma unroll
            for (int j = 0; j < 4; ++j) {
                int row = wn + j * 16 + (lane & 15);
                b_frag[j] = *(const short8*)(Bs + row * BK + ((cbase ^ (row & 7)) * 8));
            }
            #pragma unroll
            for (int i = 0; i < 4; ++i)
                #pragma unroll
                for (int j = 0; j < 4; ++j)
                    acc[i][j] = __builtin_amdgcn_mfma_f32_16x16x32_bf16(a_frag[i], b_frag[j],
                                                                        acc[i][j], 0, 0, 0);
        }
        __syncthreads();
    }

    // epilogue: relu(acc + cbias) * v, reduce over this block's 128 o's.
    // C/D: col = lane&15 (o), row = (lane>>4)*4 + reg (m).  (verified rounds 1-4)
    const int col = lane & 15;
    const int q = lane >> 4;
    float vv[4], cbv[4];
    #pragma unroll
    for (int j = 0; j < 4; ++j) {
        int oc = wn + j * 16 + col;
        vv[j] = v_s[oc];
        cbv[j] = cb_s[oc];
    }
    #pragma unroll
    for (int i = 0; i < 4; ++i) {
        #pragma unroll
        for (int r = 0; r < 4; ++r) {
            float s = 0.f;
            #pragma unroll
            for (int j = 0; j < 4; ++j) {
                float e = acc[i][j][r] + cbv[j];
                e = fmaxf(e, 0.f);
                s = fmaf(e, vv[j], s);
            }
            s += __shfl_xor(s, 1);
            s += __shfl_xor(s, 2);
            s += __shfl_xor(s, 4);
            s += __shfl_xor(s, 8);
            if (col == 0) rowsum[wid >> 1][wm + i * 16 + q * 4 + r] = s;
        }
    }
    __syncthreads();
    if (tid < TM) atomicAdd(&logits[m0 + tid], rowsum[0][tid] + rowsum[1][tid]);
}

// ---------- fallback GEMM (fp32 A staged+converted in-kernel, BK=32) ---------------------
__global__ __launch_bounds__(256) void gemm_att_k(const float* __restrict__ hidden,
                                                  const float* __restrict__ enc,
                                                  const unsigned short* __restrict__ Wbf,
                                                  const float* __restrict__ Wf,
                                                  const float* __restrict__ cbias,
                                                  const float* __restrict__ v,
                                                  float* __restrict__ logits,
                                                  int use_wbf) {
    __shared__ unsigned short As[TM * 32] __attribute__((aligned(16)));
    __shared__ unsigned short Bs[TN * 32] __attribute__((aligned(16)));
    __shared__ float rowsum[2][TM];
    __shared__ float cb_s[TN];
    __shared__ float v_s[TN];

    const int tid = threadIdx.x;
    const int ntile = blockIdx.x & 7;
    const int mtile = blockIdx.x >> 3;
    const int m0 = mtile * TM;
    const int o0 = ntile * TN;
    const int batch = m0 >> 11;

    if (tid < TN) {
        cb_s[tid] = cbias[batch * NOUT + o0 + tid];
        v_s[tid] = v[o0 + tid];
    }

    const int wid = tid >> 6;
    const int lane = tid & 63;
    const int wm = (wid & 1) * 64;
    const int wn = (wid >> 1) * 64;

    f32x4 acc[4][4] = {};

    for (int kt = 0; kt < KHE; kt += 32) {
        const float* Abase = (kt < ND) ? hidden : enc;
        const int aoff = (kt < ND) ? kt : (kt - ND);
        #pragma unroll
        for (int i = 0; i < 4; ++i) {
            int p = tid + i * 256;
            int row = p >> 3, kc = p & 7;
            float4 f = *(const float4*)(Abase + (size_t)(m0 + row) * ND + aoff + kc * 4);
            ushort4v h;
            h.x = bf16_rne(f.x); h.y = bf16_rne(f.y); h.z = bf16_rne(f.z); h.w = bf16_rne(f.w);
            *(ushort4v*)(As + row * 32 + kc * 4) = h;
        }
        if (use_wbf) {
            #pragma unroll
            for (int i = 0; i < 2; ++i) {
                int u = tid + i * 256;
                int ol = u >> 2, kc = u & 3;
                ushort8v w8 = *(const ushort8v*)(Wbf + (size_t)(o0 + ol) * KHE + kt + kc * 8);
                *(ushort8v*)(Bs + ol * 32 + kc * 8) = w8;
            }
        } else {
            const int woff = (kt < ND) ? kt : (kt + ND);
            #pragma unroll
            for (int i = 0; i < 4; ++i) {
                int p = tid + i * 256;
                int row = p >> 3, kc = p & 7;
                float4 f = *(const float4*)(Wf + (size_t)(o0 + row) * 3072 + woff + kc * 4);
                ushort4v h;
                h.x = bf16_rne(f.x); h.y = bf16_rne(f.y); h.z = bf16_rne(f.z); h.w = bf16_rne(f.w);
                *(ushort4v*)(Bs + row * 32 + kc * 4) = h;
            }
        }
        __syncthreads();

        short8 a_frag[4], b_frag[4];
        #pragma unroll
        for (int i = 0; i < 4; ++i)
            a_frag[i] = *(const short8*)(As + (wm + i * 16 + (lane & 15)) * 32 + (lane >> 4) * 8);
        #pragma unroll
        for (int j = 0; j < 4; ++j)
            b_frag[j] = *(const short8*)(Bs + (wn + j * 16 + (lane & 15)) * 32 + (lane >> 4) * 8);
        #pragma unroll
        for (int i = 0; i < 4; ++i)
            #pragma unroll
            for (int j = 0; j < 4; ++j)
                acc[i][j] = __builtin_amdgcn_mfma_f32_16x16x32_bf16(a_frag[i], b_frag[j],
                                                                    acc[i][j], 0, 0, 0);
        __syncthreads();
    }

    const int col = lane & 15;
    const int q = lane >> 4;
    float vv[4], cbv[4];
    #pragma unroll
    for (int j = 0; j < 4; ++j) {
        int oc = wn + j * 16 + col;
        vv[j] = v_s[oc];
        cbv[j] = cb_s[oc];
    }
    #pragma unroll
    for (int i = 0; i < 4; ++i) {
        #pragma unroll
        for (int r = 0; r < 4; ++r) {
            float s = 0.f;
            #pragma unroll
            for (int j = 0; j < 4; ++j) {
                float e = acc[i][j][r] + cbv[j];
                e = fmaxf(e, 0.f);
                s = fmaf(e, vv[j], s);
            }
            s += __shfl_xor(s, 1);
            s += __shfl_xor(s, 2);
            s += __shfl_xor(s, 4);
            s += __shfl_xor(s, 8);
            if (col == 0) rowsum[wid >> 1][wm + i * 16 + q * 4 + r] = s;
        }
    }
    __syncthreads();
    if (tid < TM) atomicAdd(&logits[m0 + tid], rowsum[0][tid] + rowsum[1][tid]);
}

// ---------- softmax over S per batch -----------------------------------------------------
__global__ __launch_bounds__(256) void softmax_k(const float* __restrict__ logits,
                                                 float* __restrict__ out) {
    const int b = blockIdx.x;
    const int tid = threadIdx.x;
    const int lane = tid & 63, wid = tid >> 6;
    __shared__ float redmax[4];
    __shared__ float redsum[4];
    const float* L = logits + (size_t)b * NS;
    float x[8];
    float mx = -3.4e38f;
    #pragma unroll
    for (int i = 0; i < 8; ++i) {
        x[i] = L[tid + i * 256];
        mx = fmaxf(mx, x[i]);
    }
    #pragma unroll
    for (int m = 1; m < 64; m <<= 1) mx = fmaxf(mx, __shfl_xor(mx, m));
    if (lane == 0) redmax[wid] = mx;
    __syncthreads();
    mx = fmaxf(fmaxf(redmax[0], redmax[1]), fmaxf(redmax[2], redmax[3]));
    float sum = 0.f;
    #pragma unroll
    for (int i = 0; i < 8; ++i) {
        x[i] = expf(x[i] - mx);
        sum += x[i];
    }
    #pragma unroll
    for (int m = 1; m < 64; m <<= 1) sum += __shfl_xor(sum, m);
    if (lane == 0) redsum[wid] = sum;
    __syncthreads();
    float inv = 1.0f / (redsum[0] + redsum[1] + redsum[2] + redsum[3]);
    #pragma unroll
    for (int i = 0; i < 8; ++i) out[(size_t)b * NS + tid + i * 256] = x[i] * inv;
}

extern "C" void kernel_launch(void* const* d_in, const int* in_sizes, int n_in,
                              void* d_out, int out_size, void* d_ws, size_t ws_size,
                              hipStream_t stream) {
    const float* hidden = (const float*)d_in[0];
    const float* enc    = (const float*)d_in[1];
    const float* c_t    = (const float*)d_in[2];
    const float* W      = (const float*)d_in[3];
    const float* bias   = (const float*)d_in[4];
    const float* v      = (const float*)d_in[5];
    float* out = (float*)d_out;

    char* ws = (char*)d_ws;
    float* logits = (float*)ws;                             // 131072 B
    float* cbias  = (float*)(ws + 131072);                  //  65536 B
    unsigned short* Wbf = (unsigned short*)(ws + 196608);   // 4 MiB
    unsigned short* Abf = (unsigned short*)(ws + 196608 + 4194304);  // 128 MiB
    const size_t need_wbf = 196608 + (size_t)NOUT * KHE * 2;
    const size_t need_abf = need_wbf + (size_t)NM * KHE * 2;

    if (ws_size >= need_abf) {
        prep_k<<<PREP_ACONV + PREP_WCONV + PREP_CBIAS + PREP_ZERO, 256, 0, stream>>>(
            hidden, enc, c_t, W, bias, Abf, Wbf, cbias, logits);
        gemm_att_bf_k<<<(NM / TM) * (NOUT / TN), 256, 0, stream>>>(Abf, Wbf, cbias, v, logits);
    } else if (ws_size >= need_wbf) {
        hipMemsetAsync(logits, 0, NM * sizeof(float), stream);
        cbias_k<<<NOUT / 4, 256, 0, stream>>>(c_t, W, bias, cbias);
        wconv_k<<<(NOUT * KHE / 4) / 256, 256, 0, stream>>>(W, Wbf);
        gemm_att_k<<<(NM / TM) * (NOUT / TN), 256, 0, stream>>>(hidden, enc, Wbf, W, cbias, v,
                                                                logits, 1);
    } else {
        hipMemsetAsync(logits, 0, NM * sizeof(float), stream);
        cbias_k<<<NOUT / 4, 256, 0, stream>>>(c_t, W, bias, cbias);
        gemm_att_k<<<(NM / TM) * (NOUT / TN), 256, 0, stream>>>(hidden, enc, Wbf, W, cbias, v,
                                                                logits, 0);
    }
    softmax_k<<<NB, 256, 0, stream>>>(logits, out);
}

// Round 6
// 457.236 us; speedup vs baseline: 1.1029x; 1.0963x over previous
//
#include <hip/hip_runtime.h>
#include <hip/hip_bf16.h>

// B=16, S=2048, D=1024, OUT=1024.
// attn[b,s] = softmax_s( sum_o v[o]*relu( [hidden|c_t|enc].W[o,:] + bias[o] ) )
// c_t term hoisted to cbias[b,o]; main GEMM: A[32768,2048](bf16) x W_he[1024,2048](bf16).
// R3: BK=64 XOR swizzle -> 0 conflicts, 191us. R4: XCD remap cut FETCH 4x but -8% (L2
// same-tile contention) -> reverted. R6: TM=256xTN=128, 512thr: staged bytes -25%,
// barrier events/CU halved.

typedef __attribute__((ext_vector_type(8))) short short8;
typedef __attribute__((ext_vector_type(4))) float f32x4;
typedef __attribute__((ext_vector_type(8))) unsigned short ushort8v;
typedef __attribute__((ext_vector_type(4))) unsigned short ushort4v;

#define NB 16
#define NS 2048
#define ND 1024
#define NOUT 1024
#define NM (NB * NS)   // 32768 rows
#define KHE 2048       // hidden+encoder K
#define TM 256
#define TN 128
#define BK 64
#define NROWS (TM + TN)   // 384 staged rows/slab

// prep_k block ranges
#define PREP_ACONV 16384
#define PREP_WCONV 2048
#define PREP_CBIAS 256
#define PREP_ZERO 32

__device__ __forceinline__ unsigned short bf16_rne(float x) {
    unsigned int u = __float_as_uint(x);
    unsigned int r = (u + 0x7fffu + ((u >> 16) & 1u)) >> 16;
    return (unsigned short)r;
}

__device__ __forceinline__ void gload_lds16(const unsigned short* g, unsigned short* l) {
    __builtin_amdgcn_global_load_lds(
        (const __attribute__((address_space(1))) void*)g,
        (__attribute__((address_space(3))) void*)l, 16, 0, 0);
}

// ---------- fused prep: A-convert | W-convert | cbias | zero-logits ----------------------
__global__ __launch_bounds__(256) void prep_k(const float* __restrict__ hidden,
                                              const float* __restrict__ enc,
                                              const float* __restrict__ c_t,
                                              const float* __restrict__ W,
                                              const float* __restrict__ bias,
                                              unsigned short* __restrict__ Abf,
                                              unsigned short* __restrict__ Wbf,
                                              float* __restrict__ cbias,
                                              float* __restrict__ logits) {
    const int bid = blockIdx.x;
    const int tid = threadIdx.x;
    if (bid < PREP_ACONV) {
        // A: [hidden|enc] fp32 -> Abf [32768][2048] bf16, 16 elems/thread
        size_t c = (size_t)bid * 256 + tid;
        size_t m = c >> 7;
        int k = (int)(c & 127) * 16;
        const float* src = (k < ND) ? (hidden + m * ND + k) : (enc + m * ND + (k - ND));
        float4 f0 = ((const float4*)src)[0];
        float4 f1 = ((const float4*)src)[1];
        float4 f2 = ((const float4*)src)[2];
        float4 f3 = ((const float4*)src)[3];
        ushort8v h0, h1;
        h0[0] = bf16_rne(f0.x); h0[1] = bf16_rne(f0.y); h0[2] = bf16_rne(f0.z); h0[3] = bf16_rne(f0.w);
        h0[4] = bf16_rne(f1.x); h0[5] = bf16_rne(f1.y); h0[6] = bf16_rne(f1.z); h0[7] = bf16_rne(f1.w);
        h1[0] = bf16_rne(f2.x); h1[1] = bf16_rne(f2.y); h1[2] = bf16_rne(f2.z); h1[3] = bf16_rne(f2.w);
        h1[4] = bf16_rne(f3.x); h1[5] = bf16_rne(f3.y); h1[6] = bf16_rne(f3.z); h1[7] = bf16_rne(f3.w);
        *(ushort8v*)(Abf + m * KHE + k) = h0;
        *(ushort8v*)(Abf + m * KHE + k + 8) = h1;
    } else if (bid < PREP_ACONV + PREP_WCONV) {
        int idx = (bid - PREP_ACONV) * 256 + tid;
        int o = idx >> 9;
        int k = (idx & 511) * 4;
        int off = (k < ND) ? k : (k + ND);
        float4 f = *(const float4*)(W + (size_t)o * 3072 + off);
        ushort4v h;
        h.x = bf16_rne(f.x); h.y = bf16_rne(f.y); h.z = bf16_rne(f.z); h.w = bf16_rne(f.w);
        *(ushort4v*)(Wbf + (size_t)o * KHE + k) = h;
    } else if (bid < PREP_ACONV + PREP_WCONV + PREP_CBIAS) {
        int o = (bid - PREP_ACONV - PREP_WCONV) * 4 + (tid >> 6);
        int lane = tid & 63;
        const float* w = W + (size_t)o * 3072 + ND;
        float wr[16];
        #pragma unroll
        for (int j = 0; j < 16; ++j) wr[j] = w[lane + j * 64];
        float bo = bias[o];
        for (int b = 0; b < NB; ++b) {
            const float* cc = c_t + (size_t)b * ND;
            float s = 0.f;
            #pragma unroll
            for (int j = 0; j < 16; ++j) s = fmaf(cc[lane + j * 64], wr[j], s);
            #pragma unroll
            for (int m = 1; m < 64; m <<= 1) s += __shfl_xor(s, m);
            if (lane == 0) cbias[b * NOUT + o] = s + bo;
        }
    } else {
        int idx = (bid - PREP_ACONV - PREP_WCONV - PREP_CBIAS) * 256 + tid;
        ((float4*)logits)[idx] = make_float4(0.f, 0.f, 0.f, 0.f);
    }
}

// ---------- standalone prep pieces (ws-fallback path only) -------------------------------
__global__ __launch_bounds__(256) void wconv_k(const float* __restrict__ W,
                                               unsigned short* __restrict__ Wbf) {
    int idx = blockIdx.x * 256 + threadIdx.x;
    int o = idx >> 9;
    int k = (idx & 511) * 4;
    int off = (k < ND) ? k : (k + ND);
    float4 f = *(const float4*)(W + (size_t)o * 3072 + off);
    ushort4v h;
    h.x = bf16_rne(f.x); h.y = bf16_rne(f.y); h.z = bf16_rne(f.z); h.w = bf16_rne(f.w);
    *(ushort4v*)(Wbf + (size_t)o * KHE + k) = h;
}

__global__ __launch_bounds__(256) void cbias_k(const float* __restrict__ c_t,
                                               const float* __restrict__ W,
                                               const float* __restrict__ bias,
                                               float* __restrict__ cbias) {
    int o = blockIdx.x * 4 + (threadIdx.x >> 6);
    int lane = threadIdx.x & 63;
    const float* w = W + (size_t)o * 3072 + ND;
    float wr[16];
    #pragma unroll
    for (int j = 0; j < 16; ++j) wr[j] = w[lane + j * 64];
    float bo = bias[o];
    for (int b = 0; b < NB; ++b) {
        const float* c = c_t + (size_t)b * ND;
        float s = 0.f;
        #pragma unroll
        for (int j = 0; j < 16; ++j) s = fmaf(c[lane + j * 64], wr[j], s);
        #pragma unroll
        for (int m = 1; m < 64; m <<= 1) s += __shfl_xor(s, m);
        if (lane == 0) cbias[b * NOUT + o] = s + bo;
    }
}

// ---------- fast GEMM: 256x128 block, 8 waves, BK=64 XOR swizzle, plain mapping ----------
// LDS: one flat region, rows 0..255 = A-tile, 256..383 = B-tile; row stride 128 B spans
// all 32 banks. Slot sigma of row rho holds global 16B-chunk sigma^(rho&7).
// Staging: each wave stages 48 rows = 6 issues x 8 rows; lane l -> row l>>3, slot l&7,
// fetches chunk (l&7)^(l>>3). ds_read: chunk cbase at slot cbase^(row&7) -> 0 conflicts
// (verified R3/R5). __launch_bounds__(512,4) forces VGPR<=128 -> 2 blocks/CU (16 waves).
__global__ __launch_bounds__(512, 4) void gemm_att_bf_k(const unsigned short* __restrict__ Abf,
                                                        const unsigned short* __restrict__ Wbf,
                                                        const float* __restrict__ cbias,
                                                        const float* __restrict__ v,
                                                        float* __restrict__ logits) {
    __shared__ unsigned short Ls[NROWS * BK] __attribute__((aligned(16)));  // 48 KiB
    __shared__ float rowsum[2][TM];   // 2 KiB
    __shared__ float cb_s[TN];
    __shared__ float v_s[TN];

    const int tid = threadIdx.x;
    const int bid = blockIdx.x;
    const int ntile = bid & 7;       // 8 ntiles
    const int mtile = bid >> 3;      // 128 mtiles
    const int m0 = mtile * TM;       // 2048 % 256 == 0 -> no batch straddle
    const int o0 = ntile * TN;
    const int batch = m0 >> 11;

    if (tid < TN) {
        cb_s[tid] = cbias[batch * NOUT + o0 + tid];
        v_s[tid] = v[o0 + tid];
    }

    const int wid = tid >> 6;        // 0..7
    const int lane = tid & 63;
    const int wm = (wid & 3) * 64;   // 4 m-waves
    const int wn = (wid >> 2) * 64;  // 2 n-waves

    // staging lane geometry
    const int srow = lane >> 3;             // 0..7
    const int schunk = (lane & 7) ^ srow;   // swizzled 16B chunk

    f32x4 acc[4][4] = {};

    for (int kt = 0; kt < KHE; kt += BK) {
        #pragma unroll
        for (int t = 0; t < 6; ++t) {
            const int r0 = wid * 48 + t * 8;    // wave-uniform issue base row (8-aligned)
            const unsigned short* src = (r0 < TM)
                ? (Abf + (size_t)(m0 + r0 + srow) * KHE + kt + schunk * 8)
                : (Wbf + (size_t)(o0 + r0 - TM + srow) * KHE + kt + schunk * 8);
            gload_lds16(src, Ls + r0 * BK);
        }
        __syncthreads();

        #pragma unroll
        for (int s = 0; s < 2; ++s) {
            const int cbase = s * 4 + (lane >> 4);   // global k-chunk this lane needs
            short8 a_frag[4], b_frag[4];
            #pragma unroll
            for (int i = 0; i < 4; ++i) {
                int row = wm + i * 16 + (lane & 15);
                a_frag[i] = *(const short8*)(Ls + row * BK + ((cbase ^ (row & 7)) * 8));
            }
            #pragma unroll
            for (int j = 0; j < 4; ++j) {
                int row = TM + wn + j * 16 + (lane & 15);
                b_frag[j] = *(const short8*)(Ls + row * BK + ((cbase ^ (row & 7)) * 8));
            }
            #pragma unroll
            for (int i = 0; i < 4; ++i)
                #pragma unroll
                for (int j = 0; j < 4; ++j)
                    acc[i][j] = __builtin_amdgcn_mfma_f32_16x16x32_bf16(a_frag[i], b_frag[j],
                                                                        acc[i][j], 0, 0, 0);
        }
        __syncthreads();
    }

    // epilogue: relu(acc + cbias) * v, reduce over this block's 128 o's.
    // C/D: col = lane&15 (o), row = (lane>>4)*4 + reg (m).  (verified rounds 1-5)
    const int col = lane & 15;
    const int q = lane >> 4;
    float vv[4], cbv[4];
    #pragma unroll
    for (int j = 0; j < 4; ++j) {
        int oc = wn + j * 16 + col;
        vv[j] = v_s[oc];
        cbv[j] = cb_s[oc];
    }
    #pragma unroll
    for (int i = 0; i < 4; ++i) {
        #pragma unroll
        for (int r = 0; r < 4; ++r) {
            float s = 0.f;
            #pragma unroll
            for (int j = 0; j < 4; ++j) {
                float e = acc[i][j][r] + cbv[j];
                e = fmaxf(e, 0.f);
                s = fmaf(e, vv[j], s);
            }
            s += __shfl_xor(s, 1);
            s += __shfl_xor(s, 2);
            s += __shfl_xor(s, 4);
            s += __shfl_xor(s, 8);
            if (col == 0) rowsum[wid >> 2][wm + i * 16 + q * 4 + r] = s;
        }
    }
    __syncthreads();
    if (tid < TM) atomicAdd(&logits[m0 + tid], rowsum[0][tid] + rowsum[1][tid]);
}

// ---------- fallback GEMM (fp32 A staged+converted in-kernel, 128x128, BK=32) ------------
__global__ __launch_bounds__(256) void gemm_att_k(const float* __restrict__ hidden,
                                                  const float* __restrict__ enc,
                                                  const unsigned short* __restrict__ Wbf,
                                                  const float* __restrict__ Wf,
                                                  const float* __restrict__ cbias,
                                                  const float* __restrict__ v,
                                                  float* __restrict__ logits,
                                                  int use_wbf) {
    __shared__ unsigned short As[128 * 32] __attribute__((aligned(16)));
    __shared__ unsigned short Bs[128 * 32] __attribute__((aligned(16)));
    __shared__ float rowsum[2][128];
    __shared__ float cb_s[128];
    __shared__ float v_s[128];

    const int tid = threadIdx.x;
    const int ntile = blockIdx.x & 7;
    const int mtile = blockIdx.x >> 3;
    const int m0 = mtile * 128;
    const int o0 = ntile * 128;
    const int batch = m0 >> 11;

    if (tid < 128) {
        cb_s[tid] = cbias[batch * NOUT + o0 + tid];
        v_s[tid] = v[o0 + tid];
    }

    const int wid = tid >> 6;
    const int lane = tid & 63;
    const int wm = (wid & 1) * 64;
    const int wn = (wid >> 1) * 64;

    f32x4 acc[4][4] = {};

    for (int kt = 0; kt < KHE; kt += 32) {
        const float* Abase = (kt < ND) ? hidden : enc;
        const int aoff = (kt < ND) ? kt : (kt - ND);
        #pragma unroll
        for (int i = 0; i < 4; ++i) {
            int p = tid + i * 256;
            int row = p >> 3, kc = p & 7;
            float4 f = *(const float4*)(Abase + (size_t)(m0 + row) * ND + aoff + kc * 4);
            ushort4v h;
            h.x = bf16_rne(f.x); h.y = bf16_rne(f.y); h.z = bf16_rne(f.z); h.w = bf16_rne(f.w);
            *(ushort4v*)(As + row * 32 + kc * 4) = h;
        }
        if (use_wbf) {
            #pragma unroll
            for (int i = 0; i < 2; ++i) {
                int u = tid + i * 256;
                int ol = u >> 2, kc = u & 3;
                ushort8v w8 = *(const ushort8v*)(Wbf + (size_t)(o0 + ol) * KHE + kt + kc * 8);
                *(ushort8v*)(Bs + ol * 32 + kc * 8) = w8;
            }
        } else {
            const int woff = (kt < ND) ? kt : (kt + ND);
            #pragma unroll
            for (int i = 0; i < 4; ++i) {
                int p = tid + i * 256;
                int row = p >> 3, kc = p & 7;
                float4 f = *(const float4*)(Wf + (size_t)(o0 + row) * 3072 + woff + kc * 4);
                ushort4v h;
                h.x = bf16_rne(f.x); h.y = bf16_rne(f.y); h.z = bf16_rne(f.z); h.w = bf16_rne(f.w);
                *(ushort4v*)(Bs + row * 32 + kc * 4) = h;
            }
        }
        __syncthreads();

        short8 a_frag[4], b_frag[4];
        #pragma unroll
        for (int i = 0; i < 4; ++i)
            a_frag[i] = *(const short8*)(As + (wm + i * 16 + (lane & 15)) * 32 + (lane >> 4) * 8);
        #pragma unroll
        for (int j = 0; j < 4; ++j)
            b_frag[j] = *(const short8*)(Bs + (wn + j * 16 + (lane & 15)) * 32 + (lane >> 4) * 8);
        #pragma unroll
        for (int i = 0; i < 4; ++i)
            #pragma unroll
            for (int j = 0; j < 4; ++j)
                acc[i][j] = __builtin_amdgcn_mfma_f32_16x16x32_bf16(a_frag[i], b_frag[j],
                                                                    acc[i][j], 0, 0, 0);
        __syncthreads();
    }

    const int col = lane & 15;
    const int q = lane >> 4;
    float vv[4], cbv[4];
    #pragma unroll
    for (int j = 0; j < 4; ++j) {
        int oc = wn + j * 16 + col;
        vv[j] = v_s[oc];
        cbv[j] = cb_s[oc];
    }
    #pragma unroll
    for (int i = 0; i < 4; ++i) {
        #pragma unroll
        for (int r = 0; r < 4; ++r) {
            float s = 0.f;
            #pragma unroll
            for (int j = 0; j < 4; ++j) {
                float e = acc[i][j][r] + cbv[j];
                e = fmaxf(e, 0.f);
                s = fmaf(e, vv[j], s);
            }
            s += __shfl_xor(s, 1);
            s += __shfl_xor(s, 2);
            s += __shfl_xor(s, 4);
            s += __shfl_xor(s, 8);
            if (col == 0) rowsum[wid >> 1][wm + i * 16 + q * 4 + r] = s;
        }
    }
    __syncthreads();
    if (tid < 128) atomicAdd(&logits[m0 + tid], rowsum[0][tid] + rowsum[1][tid]);
}

// ---------- softmax over S per batch -----------------------------------------------------
__global__ __launch_bounds__(256) void softmax_k(const float* __restrict__ logits,
                                                 float* __restrict__ out) {
    const int b = blockIdx.x;
    const int tid = threadIdx.x;
    const int lane = tid & 63, wid = tid >> 6;
    __shared__ float redmax[4];
    __shared__ float redsum[4];
    const float* L = logits + (size_t)b * NS;
    float x[8];
    float mx = -3.4e38f;
    #pragma unroll
    for (int i = 0; i < 8; ++i) {
        x[i] = L[tid + i * 256];
        mx = fmaxf(mx, x[i]);
    }
    #pragma unroll
    for (int m = 1; m < 64; m <<= 1) mx = fmaxf(mx, __shfl_xor(mx, m));
    if (lane == 0) redmax[wid] = mx;
    __syncthreads();
    mx = fmaxf(fmaxf(redmax[0], redmax[1]), fmaxf(redmax[2], redmax[3]));
    float sum = 0.f;
    #pragma unroll
    for (int i = 0; i < 8; ++i) {
        x[i] = expf(x[i] - mx);
        sum += x[i];
    }
    #pragma unroll
    for (int m = 1; m < 64; m <<= 1) sum += __shfl_xor(sum, m);
    if (lane == 0) redsum[wid] = sum;
    __syncthreads();
    float inv = 1.0f / (redsum[0] + redsum[1] + redsum[2] + redsum[3]);
    #pragma unroll
    for (int i = 0; i < 8; ++i) out[(size_t)b * NS + tid + i * 256] = x[i] * inv;
}

extern "C" void kernel_launch(void* const* d_in, const int* in_sizes, int n_in,
                              void* d_out, int out_size, void* d_ws, size_t ws_size,
                              hipStream_t stream) {
    const float* hidden = (const float*)d_in[0];
    const float* enc    = (const float*)d_in[1];
    const float* c_t    = (const float*)d_in[2];
    const float* W      = (const float*)d_in[3];
    const float* bias   = (const float*)d_in[4];
    const float* v      = (const float*)d_in[5];
    float* out = (float*)d_out;

    char* ws = (char*)d_ws;
    float* logits = (float*)ws;                             // 131072 B
    float* cbias  = (float*)(ws + 131072);                  //  65536 B
    unsigned short* Wbf = (unsigned short*)(ws + 196608);   // 4 MiB
    unsigned short* Abf = (unsigned short*)(ws + 196608 + 4194304);  // 128 MiB
    const size_t need_wbf = 196608 + (size_t)NOUT * KHE * 2;
    const size_t need_abf = need_wbf + (size_t)NM * KHE * 2;

    if (ws_size >= need_abf) {
        prep_k<<<PREP_ACONV + PREP_WCONV + PREP_CBIAS + PREP_ZERO, 256, 0, stream>>>(
            hidden, enc, c_t, W, bias, Abf, Wbf, cbias, logits);
        gemm_att_bf_k<<<(NM / TM) * (NOUT / TN), 512, 0, stream>>>(Abf, Wbf, cbias, v, logits);
    } else if (ws_size >= need_wbf) {
        hipMemsetAsync(logits, 0, NM * sizeof(float), stream);
        cbias_k<<<NOUT / 4, 256, 0, stream>>>(c_t, W, bias, cbias);
        wconv_k<<<(NOUT * KHE / 4) / 256, 256, 0, stream>>>(W, Wbf);
        gemm_att_k<<<(NM / 128) * (NOUT / 128), 256, 0, stream>>>(hidden, enc, Wbf, W, cbias, v,
                                                                  logits, 1);
    } else {
        hipMemsetAsync(logits, 0, NM * sizeof(float), stream);
        cbias_k<<<NOUT / 4, 256, 0, stream>>>(c_t, W, bias, cbias);
        gemm_att_k<<<(NM / 128) * (NOUT / 128), 256, 0, stream>>>(hidden, enc, Wbf, W, cbias, v,
                                                                  logits, 0);
    }
    softmax_k<<<NB, 256, 0, stream>>>(logits, out);
}